// Round 4
// baseline (259.299 us; speedup 1.0000x reference)
//
#include <hip/hip_runtime.h>
#include <hip/hip_bf16.h>

typedef __hip_bfloat16 bf16;
typedef unsigned short u16;
typedef __attribute__((ext_vector_type(8))) short bf16x8;      // MFMA A/B frag: 8 bf16 = 4 VGPRs
typedef __attribute__((ext_vector_type(16))) float f32x16;     // 32x32 MFMA C/D frag
typedef __attribute__((ext_vector_type(8))) unsigned short u16x8;

#define KD 1024
#define HD 1024
#define BSZ 8192
#define BM 128
#define BN 64
#define BK 32

// ws layout (bytes): wt [0, 12582912) | xb [12582912, +16777216) | hb [29360128, +16777216)
#define WS_XB 12582912
#define WS_HB 29360128

__device__ __forceinline__ u16 f2b(float f) {
    return __builtin_bit_cast(u16, __float2bfloat16(f));
}

// ---- async global->LDS, 16B per lane, wave-uniform LDS base + lane*16 ----
__device__ __forceinline__ void gload16(const void* g, u16* smem, int lds_byte_off) {
    __builtin_amdgcn_global_load_lds(
        (const __attribute__((address_space(1))) void*)g,
        (__attribute__((address_space(3))) void*)((char*)smem + lds_byte_off),
        16, 0, 0);
}

// ---------------------------------------------------------------------------
// Prep (single launch). Blocks [0,3072): transpose+cast weights [g][k][n] f32
// -> wt[g][n][k] bf16. Blocks [3072,7168): cast x,h f32 -> bf16.
// BOTH outputs use a 16B-chunk XOR swizzle: within each 4-chunk (32-k) group,
// chunk c of row R is stored at c ^ ((R>>1)&3). global_load_lds stages rows
// contiguously, so this lands fragments on distinct LDS banks (2-way max).
// ---------------------------------------------------------------------------
__global__ __launch_bounds__(256) void prep_all(
    const float* __restrict__ x, const float* __restrict__ h,
    const float* __restrict__ wx, const float* __restrict__ wh,
    u16* __restrict__ xb, u16* __restrict__ hb, u16* __restrict__ wtp)
{
    int b = blockIdx.x;
    if (b < 3072) {
        // transpose: cid enumerates (g, K8, n); lanes n-consecutive -> coalesced reads
        int cid = b * 256 + threadIdx.x;   // 0 .. 786431
        int n    = cid & 1023;
        int rest = cid >> 10;
        int K8   = rest & 127;             // k-chunk (8 floats)
        int g    = rest >> 7;
        const float* src = (g < 3) ? (wx + (size_t)g * KD * HD)
                                   : (wh + (size_t)(g - 3) * KD * HD);
        u16x8 v;
        #pragma unroll
        for (int e = 0; e < 8; e++)
            v[e] = f2b(src[(size_t)(K8 * 8 + e) * HD + n]);
        int K8d = (K8 & ~3) | ((K8 & 3) ^ ((n >> 1) & 3));
        *(u16x8*)(wtp + (size_t)g * KD * HD + (size_t)n * KD + K8d * 8) = v;
    } else {
        // convert x and h; one 8-elem chunk each per thread
        int cid = (b - 3072) * 256 + threadIdx.x;   // 0 .. 1048575
        int row = cid >> 7;                         // 128 chunks per 1024-k row
        int K8  = cid & 127;
        int K8d = (K8 & ~3) | ((K8 & 3) ^ ((row >> 1) & 3));
        size_t so = (size_t)cid * 8;
        size_t dO = (size_t)row * KD + K8d * 8;
        float4 a0 = *(const float4*)(x + so);
        float4 a1 = *(const float4*)(x + so + 4);
        float4 b0 = *(const float4*)(h + so);
        float4 b1 = *(const float4*)(h + so + 4);
        u16x8 vx, vh;
        vx[0]=f2b(a0.x); vx[1]=f2b(a0.y); vx[2]=f2b(a0.z); vx[3]=f2b(a0.w);
        vx[4]=f2b(a1.x); vx[5]=f2b(a1.y); vx[6]=f2b(a1.z); vx[7]=f2b(a1.w);
        vh[0]=f2b(b0.x); vh[1]=f2b(b0.y); vh[2]=f2b(b0.z); vh[3]=f2b(b0.w);
        vh[4]=f2b(b1.x); vh[5]=f2b(b1.y); vh[6]=f2b(b1.z); vh[7]=f2b(b1.w);
        *(u16x8*)(xb + dO) = vx;
        *(u16x8*)(hb + dO) = vh;
    }
}

// ---------------------------------------------------------------------------
// Fused GRU GEMM, 32x32x16 MFMA. Block 128x64, 4 waves (2m x 2n), wave tile
// 64x32 = 2 m-subtiles. 4 acc sets: r(shared x+h), z(shared), nx, nh.
// A-frag: A[m=lane&31][k=(lane>>5)*8+j]; B-frag: B[k=(lane>>5)*8+j][n=lane&31]
// C/D: col=lane&31, row=(reg&3)+8*(reg>>2)+4*(lane>>5)  [m74/m101 verified].
// LDS (u16 idx): x [0,4096) h [4096,8192) w_g at 8192+g*2048; rows = 32 u16,
// 16B chunks XOR-swizzled by ((row>>1)&3) to kill bank conflicts.
// ---------------------------------------------------------------------------
__global__ __launch_bounds__(256, 2) void gru_fused_fast(
    const u16* __restrict__ xb, const u16* __restrict__ hb,
    const u16* __restrict__ wt,
    const float* __restrict__ bxf, const float* __restrict__ bhf,
    const float* __restrict__ hidf, float* __restrict__ outf)
{
    __shared__ u16 smem[20480];   // 40 KiB
    const int t     = threadIdx.x;
    const int lane  = t & 63;
    const int w     = t >> 6;
    const int wm    = w >> 1, wn = w & 1;
    const int l31   = lane & 31;
    const int khalf = lane >> 5;
    // XCD swizzle: blocks lin%8 land on one XCD; give each XCD 2 n-blocks so
    // its 1.57 MB weight slice stays L2-resident.
    const int lin  = blockIdx.x;
    const int nblk = (lin & 7) * 2 + ((lin >> 3) & 1);
    const int mblk = lin >> 4;
    const int m0   = mblk * BM;
    const int n0   = nblk * BN;

    const int row4 = t >> 2;
    const int e8   = (t & 3) * 8;
    const u16* gx0 = xb + (size_t)(m0 + row4) * KD + e8;
    const u16* gx1 = gx0 + (size_t)64 * KD;
    const u16* gh0 = hb + (size_t)(m0 + row4) * KD + e8;
    const u16* gh1 = gh0 + (size_t)64 * KD;
    const u16* gw0 = wt + (size_t)(n0 + row4) * KD + e8;
    const int ldsl = w * 1024;   // wave-uniform LDS byte base (lane adds *16)

    f32x16 acc[4][2];   // [set r,z,nx,nh][msub]
    #pragma unroll
    for (int a = 0; a < 4; a++)
        #pragma unroll
        for (int m = 0; m < 2; m++)
            #pragma unroll
            for (int r = 0; r < 16; r++)
                acc[a][m][r] = 0.f;

    // per-lane fragment LDS offsets (u16 units), swizzle folded in
    int aoff[2][2], woff[2];
    #pragma unroll
    for (int m = 0; m < 2; m++) {
        int R = wm * 64 + m * 32 + l31;
        int s = (R >> 1) & 3;
        #pragma unroll
        for (int kk = 0; kk < 2; kk++) {
            int q = kk * 2 + khalf;
            aoff[m][kk] = R * 32 + ((q ^ s) * 8);
        }
    }
    {
        int nl = wn * 32 + l31;
        int s = (nl >> 1) & 3;
        #pragma unroll
        for (int kk = 0; kk < 2; kk++) {
            int q = kk * 2 + khalf;
            woff[kk] = 8192 + nl * 32 + ((q ^ s) * 8);
        }
    }

    for (int k0 = 0; k0 < KD; k0 += BK) {
        gload16(gx0, smem, ldsl);
        gload16(gx1, smem, 4096 + ldsl);
        gload16(gh0, smem, 8192 + ldsl);
        gload16(gh1, smem, 12288 + ldsl);
        #pragma unroll
        for (int g = 0; g < 6; g++)
            gload16(gw0 + (size_t)g * KD * HD, smem, 16384 + g * 4096 + ldsl);
        __syncthreads();
        gx0 += BK; gx1 += BK; gh0 += BK; gh1 += BK; gw0 += BK;

        bf16x8 ax[2][2], ah[2][2];
        #pragma unroll
        for (int m = 0; m < 2; m++)
            #pragma unroll
            for (int kk = 0; kk < 2; kk++) {
                ax[m][kk] = *(const bf16x8*)&smem[aoff[m][kk]];
                ah[m][kk] = *(const bf16x8*)&smem[4096 + aoff[m][kk]];
            }
        #pragma unroll
        for (int p = 0; p < 3; p++) {        // gates r, z, n
            bf16x8 bwx[2], bwh[2];
            #pragma unroll
            for (int kk = 0; kk < 2; kk++) {
                bwx[kk] = *(const bf16x8*)&smem[woff[kk] + p * 2048];
                bwh[kk] = *(const bf16x8*)&smem[woff[kk] + (p + 3) * 2048];
            }
            #pragma unroll
            for (int m = 0; m < 2; m++)
                #pragma unroll
                for (int kk = 0; kk < 2; kk++) {
                    if (p < 2) {
                        acc[p][m] = __builtin_amdgcn_mfma_f32_32x32x16_bf16(ax[m][kk], bwx[kk], acc[p][m], 0, 0, 0);
                        acc[p][m] = __builtin_amdgcn_mfma_f32_32x32x16_bf16(ah[m][kk], bwh[kk], acc[p][m], 0, 0, 0);
                    } else {
                        acc[2][m] = __builtin_amdgcn_mfma_f32_32x32x16_bf16(ax[m][kk], bwx[kk], acc[2][m], 0, 0, 0);
                        acc[3][m] = __builtin_amdgcn_mfma_f32_32x32x16_bf16(ah[m][kk], bwh[kk], acc[3][m], 0, 0, 0);
                    }
                }
        }
        __syncthreads();
    }

    // ---- epilogue ----
    const int col = n0 + wn * 32 + l31;
    const float bR  = bxf[col]          + bhf[col];
    const float bZ  = bxf[HD + col]     + bhf[HD + col];
    const float bXN = bxf[2 * HD + col];
    const float bHN = bhf[2 * HD + col];
    #pragma unroll
    for (int m = 0; m < 2; m++)
        #pragma unroll
        for (int r = 0; r < 16; r++) {
            int row = m0 + wm * 64 + m * 32 + (r & 3) + 8 * (r >> 2) + 4 * khalf;
            size_t idx = (size_t)row * HD + col;
            float vr = acc[0][m][r] + bR;
            vr = 1.f / (1.f + __expf(-vr));
            float vz = acc[1][m][r] + bZ;
            vz = 1.f / (1.f + __expf(-vz));
            float vn = (acc[2][m][r] + bXN) + vr * (acc[3][m][r] + bHN);
            float e2 = __expf(2.f * vn);
            vn = 1.f - 2.f / (e2 + 1.f);
            outf[idx] = (1.f - vz) * vn + vz * hidf[idx];
        }
}

extern "C" void kernel_launch(void* const* d_in, const int* in_sizes, int n_in,
                              void* d_out, int out_size, void* d_ws, size_t ws_size,
                              hipStream_t stream) {
    const float* x   = (const float*)d_in[0];
    const float* hid = (const float*)d_in[1];
    const float* wx  = (const float*)d_in[2];
    const float* wh  = (const float*)d_in[3];
    const float* bx  = (const float*)d_in[4];
    const float* bh  = (const float*)d_in[5];
    float* out = (float*)d_out;

    char* ws = (char*)d_ws;
    u16* wt = (u16*)ws;
    u16* xb = (u16*)(ws + WS_XB);
    u16* hb = (u16*)(ws + WS_HB);

    prep_all<<<7168, 256, 0, stream>>>(x, hid, wx, wh, xb, hb, wt);
    gru_fused_fast<<<1024, 256, 0, stream>>>(xb, hb, wt, bx, bh, hid, out);
}